// Round 2
// baseline (989.971 us; speedup 1.0000x reference)
//
#include <hip/hip_runtime.h>

// SparseMinCostFlow, fused single-kernel version.
// N=8192, E=262144, 10 iterations, dense NxN fp32 out (256 MB).
//
// Two block teams inside one kernel:
//   flow team (blocks 0..FBLK-1): each thread owns EPT=4 edges (regs cached),
//     runs all 10 iterations with a device-scope counting barrier between
//     scatter(inflow_it) and gather(inflow_it) of the next iteration.
//   zero team (blocks FBLK..): clears the 256 MB output concurrently, then
//     signals ctrs[1]; flow team waits on it before the final dense scatter.
// Barrier counters live in ws and are re-zeroed by init_ws every call
// (ws is re-poisoned 0xAA before each timed launch).

#define NN 8192
#define EE 262144
#define FBLK 256
#define ZBLK 1792
#define THREADS 256
#define EPT 4   // EE / (FBLK*THREADS)

__global__ void init_ws(float* __restrict__ inflow, unsigned* __restrict__ ctrs) {
    int i = blockIdx.x * blockDim.x + threadIdx.x;
    if (i < 10 * NN) inflow[i] = 0.f;
    if (i < 2) ctrs[i] = 0u;
}

// Counting barrier for the flow team only. Monotonic target => no reset races.
__device__ __forceinline__ void flow_barrier(unsigned* ctr, unsigned target) {
    __syncthreads();
    if (threadIdx.x == 0) {
        __hip_atomic_fetch_add(ctr, 1u, __ATOMIC_RELEASE, __HIP_MEMORY_SCOPE_AGENT);
        while (__hip_atomic_load(ctr, __ATOMIC_ACQUIRE, __HIP_MEMORY_SCOPE_AGENT) < target)
            __builtin_amdgcn_s_sleep(2);
    }
    __syncthreads();
    __threadfence();  // device-scope acquire: see other blocks' atomics (G16)
}

__global__ void __launch_bounds__(THREADS) fused(
        const float* __restrict__ values, const float* __restrict__ dem,
        const int* __restrict__ rows, const int* __restrict__ cols,
        float* __restrict__ out, float* __restrict__ inflow,
        unsigned* __restrict__ ctrs) {
    const int bid = blockIdx.x;
    if (bid < FBLK) {
        // ---------------- flow team ----------------
        const int tid = bid * THREADS + threadIdx.x;   // 0..65535
        int r[EPT], c[EPT];
        float v[EPT], dr[EPT];
        #pragma unroll
        for (int j = 0; j < EPT; ++j) {
            int e = tid + j * (FBLK * THREADS);        // coalesced
            r[j] = rows[e];
            c[j] = cols[e];
            v[j] = values[e];
        }
        #pragma unroll
        for (int j = 0; j < EPT; ++j) dr[j] = dem[r[j]];

        const float* prev = inflow;                    // inflow_0 == zeros
        for (int it = 1; it <= 9; ++it) {
            float* next = inflow + it * NN;
            #pragma unroll
            for (int j = 0; j < EPT; ++j) {
                float adj = fmaxf(prev[r[j]] - dr[j], 0.f);
                atomicAdd(&next[c[j]], v[j] * adj);
            }
            flow_barrier(&ctrs[0], (unsigned)(it * FBLK));
            prev = next;
        }
        // wait for zero team before touching out
        if (threadIdx.x == 0) {
            while (__hip_atomic_load(&ctrs[1], __ATOMIC_ACQUIRE, __HIP_MEMORY_SCOPE_AGENT)
                   < (unsigned)ZBLK)
                __builtin_amdgcn_s_sleep(2);
        }
        __syncthreads();
        __threadfence();
        #pragma unroll
        for (int j = 0; j < EPT; ++j) {
            float adj = fmaxf(prev[r[j]] - dr[j], 0.f);
            atomicAdd(&out[(long)r[j] * NN + c[j]], v[j] * adj);
        }
    } else {
        // ---------------- zero team ----------------
        const long zid = (long)(bid - FBLK) * THREADS + threadIdx.x;
        const long zstride = (long)ZBLK * THREADS;
        float4* o4 = (float4*)out;
        const long n4 = (long)NN * NN / 4;             // 16M float4
        const float4 z = make_float4(0.f, 0.f, 0.f, 0.f);
        for (long i = zid; i < n4; i += zstride) o4[i] = z;
        __threadfence();                               // release my stores
        __syncthreads();
        if (threadIdx.x == 0)
            __hip_atomic_fetch_add(&ctrs[1], 1u, __ATOMIC_RELEASE, __HIP_MEMORY_SCOPE_AGENT);
    }
}

extern "C" void kernel_launch(void* const* d_in, const int* in_sizes, int n_in,
                              void* d_out, int out_size, void* d_ws, size_t ws_size,
                              hipStream_t stream) {
    const float* values = (const float*)d_in[0];
    const float* dem    = (const float*)d_in[1];
    const int*   rows   = (const int*)d_in[2];
    const int*   cols   = (const int*)d_in[3];
    float* out = (float*)d_out;

    float*    inflow = (float*)d_ws;                            // 10*NN floats
    unsigned* ctrs   = (unsigned*)((char*)d_ws + 10 * NN * sizeof(float));

    init_ws<<<(10 * NN + THREADS - 1) / THREADS, THREADS, 0, stream>>>(inflow, ctrs);
    fused<<<FBLK + ZBLK, THREADS, 0, stream>>>(values, dem, rows, cols, out, inflow, ctrs);
}

// Round 3
// 407.298 us; speedup vs baseline: 2.4306x; 2.4306x over previous
//
#include <hip/hip_runtime.h>

// SparseMinCostFlow — multi-kernel, zero-fill hidden under flow iterations.
// N=8192, E=262144, 10 iterations, dense NxN fp32 out (256 MB).
//
// Lesson from round 2: software grid barriers on 8-XCD MI355X cost ~80us each
// (agent-scope spin loads = fabric storm, FETCH_SIZE blew up to 4.2 GB).
// Kernel-launch boundaries in a captured graph cost ~2-4us. Use boundaries.
//
// Structure (12 stream ops, all ordering via launch boundaries):
//   hipMemsetAsync     : zero 10 inflow buffers in d_ws (320 KB, ~2us)
//   flow_zero  x9 (k=1..9):
//     blocks [0,FB)    : flow iter k: gather inflow_{k-1}[rows[e]],
//                        relu(.-d)*values[e] -> atomicAdd inflow_k[cols[e]]
//     blocks [FB,..)   : zero chunk k-1 (1/9 of the 256 MB output).
//     The flow part is latency-bound (~5us at <1% BW), so the 28.4 MB zero
//     chunk rides along for free.
//   scatter            : final iter 10: flow -> atomicAdd out[r*N+c].
//     Runs after all zero chunks are complete (kernel boundary) => no race.

#define NN 8192
#define EE 262144
#define THREADS 256
#define FB (EE / THREADS)          // 1024 flow blocks
#define ZB 1024                    // zero-team blocks per flow kernel
#define N4 ((long)NN * NN / 4)     // 16,777,216 float4 in output
#define CHUNK4 ((N4 + 8) / 9)      // 1,864,136 float4 per zero chunk

__global__ void __launch_bounds__(THREADS) flow_zero(
        const float* __restrict__ values, const float* __restrict__ dem,
        const int* __restrict__ rows, const int* __restrict__ cols,
        const float* __restrict__ inflow_prev, float* __restrict__ inflow_next,
        float4* __restrict__ out4, long z_lo, long z_hi) {
    const int bid = blockIdx.x;
    if (bid < FB) {
        // ---- flow team: one edge per thread ----
        int e = bid * THREADS + threadIdx.x;
        int r = rows[e];
        float adj = fmaxf(inflow_prev[r] - dem[r], 0.f);
        atomicAdd(&inflow_next[cols[e]], values[e] * adj);
    } else {
        // ---- zero team: clear output chunk [z_lo, z_hi) ----
        long i = z_lo + (long)(bid - FB) * THREADS + threadIdx.x;
        const long stride = (long)ZB * THREADS;
        const float4 z = make_float4(0.f, 0.f, 0.f, 0.f);
        for (; i < z_hi; i += stride) out4[i] = z;
    }
}

__global__ void __launch_bounds__(THREADS) scatter_final(
        const float* __restrict__ values, const float* __restrict__ dem,
        const int* __restrict__ rows, const int* __restrict__ cols,
        const float* __restrict__ inflow_prev, float* __restrict__ out) {
    int e = blockIdx.x * THREADS + threadIdx.x;
    int r = rows[e];
    float adj = fmaxf(inflow_prev[r] - dem[r], 0.f);
    atomicAdd(&out[(long)r * NN + cols[e]], values[e] * adj);
}

extern "C" void kernel_launch(void* const* d_in, const int* in_sizes, int n_in,
                              void* d_out, int out_size, void* d_ws, size_t ws_size,
                              hipStream_t stream) {
    const float* values = (const float*)d_in[0];
    const float* dem    = (const float*)d_in[1];
    const int*   rows   = (const int*)d_in[2];
    const int*   cols   = (const int*)d_in[3];
    float* out = (float*)d_out;

    // ws: 10 inflow buffers of NN floats. inflow_0 stays zero (flow0 == 0).
    float* inflow = (float*)d_ws;
    hipMemsetAsync(d_ws, 0, 10 * NN * sizeof(float), stream);

    // Iterations 1..9, each also zeroing 1/9 of the output.
    for (int k = 1; k <= 9; ++k) {
        long z_lo = (long)(k - 1) * CHUNK4;
        long z_hi = z_lo + CHUNK4; if (z_hi > N4) z_hi = N4;
        flow_zero<<<FB + ZB, THREADS, 0, stream>>>(
            values, dem, rows, cols,
            inflow + (long)(k - 1) * NN, inflow + (long)k * NN,
            (float4*)out, z_lo, z_hi);
    }

    // Iteration 10: scatter into the (now fully zeroed) dense output.
    scatter_final<<<FB, THREADS, 0, stream>>>(
        values, dem, rows, cols, inflow + 9L * NN, out);
}